// Round 15
// baseline (101.075 us; speedup 1.0000x reference)
//
#include <hip/hip_runtime.h>

#define N_NODES 50000
#define N_EDGES 800000
#define BSHIFT 7                                   // 128 nodes per bucket
#define BKT_NODES 128
#define NBKT   ((N_NODES + BKT_NODES - 1) >> BSHIFT)   // 391
#define CAP    4096                                // padded slots per bucket
#define CHUNK_EDGES 8192
#define NBIN_BLOCKS ((N_EDGES + CHUNK_EDGES - 1) / CHUNK_EDGES)  // 98
#define NPERM  (NBKT * BKT_NODES)                  // 50048
#define NB32P  (NPERM / 32)                        // 1564 blocks (32 perm slots each)
#define N_PAD  50048                               // padded node count (slice regions)
#define GEMM1_NB ((N_NODES + 63) / 64)             // 782

typedef __attribute__((ext_vector_type(8))) short short8;   // 8 bf16 (4 VGPRs)
typedef __attribute__((ext_vector_type(4))) float f32x4;    // MFMA acc
typedef __attribute__((ext_vector_type(2))) float f32x2;    // fp8 cvt result

__device__ __forceinline__ int load_idx(const void* ei, int is64, long long pos) {
  return is64 ? (int)((const long long*)ei)[pos] : ((const int*)ei)[pos];
}

// bf16 (RNE) pack helpers
__device__ __forceinline__ unsigned bfr(float f) {
  unsigned u = __float_as_uint(f);
  return (u + 0x7FFFu + ((u >> 16) & 1u)) >> 16;
}
__device__ __forceinline__ unsigned bfpk(float lo, float hi) {
  return bfr(lo) | (bfr(hi) << 16);
}
// FAST bf16 unpack-accumulate (gather2)
#define ACC_BF4F(acc, u)                                                   \
  acc.x += __uint_as_float((u).x << 16);                                   \
  acc.y += __uint_as_float((u).x);                                         \
  acc.z += __uint_as_float((u).y << 16);                                   \
  acc.w += __uint_as_float((u).y);

// fp8 e4m3 (OCP on gfx950) unpack-accumulate: uint2 = 8 fp8 -> 8 f32 adds
#define ACC_FP8(a0, a1, u) {                                               \
  f32x2 t0 = __builtin_amdgcn_cvt_pk_f32_fp8((int)(u).x, false);           \
  f32x2 t1 = __builtin_amdgcn_cvt_pk_f32_fp8((int)(u).x, true);            \
  f32x2 t2 = __builtin_amdgcn_cvt_pk_f32_fp8((int)(u).y, false);           \
  f32x2 t3 = __builtin_amdgcn_cvt_pk_f32_fp8((int)(u).y, true);            \
  a0.x += t0.x; a0.y += t0.y; a0.z += t1.x; a0.w += t1.y;                  \
  a1.x += t2.x; a1.y += t2.y; a1.z += t3.x; a1.w += t3.y; }

// ---------------------------------------------------------------------------
// prep: block 0 zeroes resv; blocks 1..88 cast W1/W2 to bf16 (native [o][k],
// W2 padded to 48 rows). Stream order guarantees resv=0 before binGemm1.
// ---------------------------------------------------------------------------
__global__ __launch_bounds__(256) void prep_kernel(const float* __restrict__ W1,
                                                   const float* __restrict__ W2,
                                                   int* __restrict__ resv,
                                                   unsigned short* __restrict__ W1bf,
                                                   unsigned short* __restrict__ W2bf) {
  int b = blockIdx.x, tid = threadIdx.x;
  if (b == 0) {
    ((int4*)resv)[tid] = make_int4(0, 0, 0, 0);   // 1024 ints
    return;
  }
  int j = (b - 1) * 256 + tid;                    // [0, 22528)
  if (j < 128 * 128) {
    W1bf[j] = (unsigned short)bfr(W1[j]);
  } else {
    int jj = j - 128 * 128;                       // [0, 6144)
    int c = jj >> 7, k = jj & 127;
    W2bf[jj] = (c < 40) ? (unsigned short)bfr(W2[c * 128 + k]) : 0;
  }
}

// ---------------------------------------------------------------------------
// Merged binPlace + gemm1 (independent work; binPlace's memory latency hides
// under gemm1's MFMA waves).
// Blocks [0, NBIN_BLOCKS): bucket partition, CHUNK=8192 edges/block.
//   pk = src | dstlow<<16 | bk<<23.
// Blocks [NBIN_BLOCKS, +GEMM1_NB): MFMA GEMM1 Y[n][o] = sum_k x[n][k]W1[o][k],
//   epilogue writes SLICE-MAJOR fp8 Ys: 2 regions of [N_PAD][64] e4m3.
// ---------------------------------------------------------------------------
__global__ __launch_bounds__(256) void binGemm1_kernel(const void* __restrict__ ei,
                                                       int* __restrict__ resv,
                                                       unsigned* __restrict__ binned,
                                                       const float* __restrict__ xin,
                                                       const unsigned short* __restrict__ W1bf,
                                                       unsigned char* __restrict__ Ysfp) {
  __shared__ unsigned short Ysh[64 * 128];       // gemm1 epilogue stage (16KB)
  __shared__ int cnt[NBKT];
  __shared__ int lbase[NBKT];
  __shared__ int sflag;
  int tid = threadIdx.x;

  if (blockIdx.x < NBIN_BLOCKS) {
    // ----- binPlace part -----
    if (tid < 64) {
      const long long* e64 = (const long long*)ei;
      long long v = e64[tid];
      unsigned long long m = __ballot(v >= 0 && v < N_NODES);
      if (tid == 0) sflag = (m == ~0ull) ? 1 : 0;
    }
    for (int i = tid; i < NBKT; i += 256) cnt[i] = 0;
    __syncthreads();
    int f = sflag;
    long long base = (long long)blockIdx.x * CHUNK_EDGES;
    unsigned pk[CHUNK_EDGES / 256];
    #pragma unroll
    for (int it = 0; it < CHUNK_EDGES / 256; ++it) {
      long long e = base + it * 256 + tid;
      unsigned p = 0xFFFFFFFFu;
      if (e < N_EDGES) {
        int src = load_idx(ei, f, e);
        int dst = load_idx(ei, f, (long long)N_EDGES + e);
        int bk = dst >> BSHIFT;
        p = (unsigned)src | ((unsigned)(dst & 127) << 16) | ((unsigned)bk << 23);
        atomicAdd(&cnt[bk], 1);
      }
      pk[it] = p;
    }
    __syncthreads();
    for (int i = tid; i < NBKT; i += 256) {
      int c = cnt[i];
      lbase[i] = c ? (i * CAP + atomicAdd(&resv[i], c)) : 0;
      cnt[i] = 0;                                 // reuse as local cursor
    }
    __syncthreads();
    #pragma unroll
    for (int it = 0; it < CHUNK_EDGES / 256; ++it) {
      unsigned p = pk[it];
      if (p != 0xFFFFFFFFu) {
        int bk = p >> 23;
        int off = atomicAdd(&cnt[bk], 1);
        binned[lbase[bk] + off] = p & 0x7FFFFFu;  // src | dstlow<<16
      }
    }
    return;
  }

  // ----- gemm1 part -----
  int wave = tid >> 6, lane = tid & 63;
  int rl = lane & 15, kg = lane >> 4;      // kg = 0..3
  int n0 = (blockIdx.x - NBIN_BLOCKS) * 64;
  int rowg = n0 + wave * 16 + rl;
  int row = (rowg < N_NODES) ? rowg : (N_NODES - 1);
  f32x4 acc[8];
  #pragma unroll
  for (int t = 0; t < 8; ++t) acc[t] = (f32x4)(0.f);
  #pragma unroll
  for (int kk = 0; kk < 4; ++kk) {
    int k0 = kk * 32 + kg * 8;
    const float* xr = xin + (size_t)row * 128 + k0;
    float4 a0 = *(const float4*)xr;
    float4 a1 = *(const float4*)(xr + 4);
    short8 a;
    a[0] = (short)bfr(a0.x); a[1] = (short)bfr(a0.y);
    a[2] = (short)bfr(a0.z); a[3] = (short)bfr(a0.w);
    a[4] = (short)bfr(a1.x); a[5] = (short)bfr(a1.y);
    a[6] = (short)bfr(a1.z); a[7] = (short)bfr(a1.w);
    #pragma unroll
    for (int t = 0; t < 8; ++t) {
      short8 b = *(const short8*)(W1bf + (t * 16 + rl) * 128 + k0);
      acc[t] = __builtin_amdgcn_mfma_f32_16x16x32_bf16(a, b, acc[t], 0, 0, 0);
    }
  }
  // C/D: col = rl, row = kg*4 + reg (within wave's 16 rows) -> bf16 LDS stage
  #pragma unroll
  for (int t = 0; t < 8; ++t) {
    #pragma unroll
    for (int reg = 0; reg < 4; ++reg)
      Ysh[(wave * 16 + kg * 4 + reg) * 128 + t * 16 + rl] =
          (unsigned short)bfr(acc[t][reg]);
  }
  __syncthreads();
  // epilogue: LDS bf16 -> fp8 e4m3, slice-major (2 regions of [N_PAD][64])
  int rows = N_NODES - n0; if (rows > 64) rows = 64;
  uint2* dstb = (uint2*)Ysfp;
  const unsigned* ysh32 = (const unsigned*)Ysh;
  for (int i = tid; i < rows * 16; i += 256) {
    int r = i >> 4, j = i & 15;            // j = 8-dim chunk (dims j*8..j*8+7)
    int base = r * 64 + j * 4;             // uint index (2 bf16 per uint)
    unsigned u0 = ysh32[base + 0], u1 = ysh32[base + 1];
    unsigned u2 = ysh32[base + 2], u3 = ysh32[base + 3];
    float d0 = __uint_as_float(u0 << 16), d1 = __uint_as_float(u0 & 0xffff0000u);
    float d2 = __uint_as_float(u1 << 16), d3 = __uint_as_float(u1 & 0xffff0000u);
    float d4 = __uint_as_float(u2 << 16), d5 = __uint_as_float(u2 & 0xffff0000u);
    float d6 = __uint_as_float(u3 << 16), d7 = __uint_as_float(u3 & 0xffff0000u);
    int wx = __builtin_amdgcn_cvt_pk_fp8_f32(d0, d1, 0, false);
    wx = __builtin_amdgcn_cvt_pk_fp8_f32(d2, d3, wx, true);
    int wy = __builtin_amdgcn_cvt_pk_fp8_f32(d4, d5, 0, false);
    wy = __builtin_amdgcn_cvt_pk_fp8_f32(d6, d7, wy, true);
    int slice = j >> 3, cs = j & 7;
    dstb[(size_t)slice * (N_PAD * 8) + (size_t)(n0 + r) * 8 + cs] =
        make_uint2((unsigned)wx, (unsigned)wy);
  }
}

// ---------------------------------------------------------------------------
// Fused csr + gather1: one block per bucket (128 nodes).
// Phase A (csr): inline scan of resv -> global base; LDS node histogram;
//   degree-sort -> pinfoL (LDS, local start) + permInfo (global start, for
//   gather2); col placed in LDS colL AND global col (for gather2).
//   NOTE: permInfo sentinel is written for ALL 128 slots (harness poisons
//   ws with 0xAA — unwritten slots would masquerade as valid nodes).
// Phase B (gather1): slice-phased fp8 gather, 8-lane groups, reading
//   colL/pinfoL from LDS. Arithmetic identical to round-13 gather1.
// ---------------------------------------------------------------------------
__global__ __launch_bounds__(256) void csrGather1_kernel(const unsigned* __restrict__ binned,
                                                         const int* __restrict__ resv,
                                                         unsigned short* __restrict__ col,
                                                         uint2* __restrict__ permInfo,
                                                         const unsigned char* __restrict__ Ysfp,
                                                         unsigned short* __restrict__ h1bf) {
  __shared__ unsigned short colL[CAP];     // 8KB, local col list
  __shared__ uint2 pinfoL[BKT_NODES];      // {local_start, node|deg<<16}
  __shared__ int red[256];
  __shared__ int ncnt[BKT_NODES];
  __shared__ int ncur[BKT_NODES];
  __shared__ int dcnt[64];
  __shared__ int dcur[64];
  int tid = threadIdx.x;
  int b = blockIdx.x;

  // ----- Phase A: csr -----
  int s = 0;
  for (int i = tid; i < b; i += 256) s += resv[i];
  red[tid] = s;
  __syncthreads();
  #pragma unroll
  for (int off = 128; off > 0; off >>= 1) {
    if (tid < off) red[tid] += red[tid + off];
    __syncthreads();
  }
  int gb = red[0];
  int c = resv[b];
  if (tid < BKT_NODES) {
    ncnt[tid] = 0;
    pinfoL[tid] = make_uint2(0u, 0xFFFFu);
    permInfo[(size_t)b * BKT_NODES + tid] = make_uint2(0u, 0xFFFFu);  // FIX: global sentinel
  }
  if (tid < 64) dcnt[tid] = 0;
  __syncthreads();
  const unsigned* bb = binned + (size_t)b * CAP;
  for (int i = tid; i < c; i += 256)
    atomicAdd(&ncnt[(bb[i] >> 16) & 127], 1);
  __syncthreads();
  if (tid == 0) {
    int a = 0;                               // LOCAL offsets
    #pragma unroll
    for (int j = 0; j < BKT_NODES; ++j) { int t = ncnt[j]; ncur[j] = a; a += t; }
  }
  __syncthreads();
  int node0 = b << BSHIFT;
  int nvalid = N_NODES - node0; if (nvalid > BKT_NODES) nvalid = BKT_NODES;
  int mystart = 0, mydeg = 0;
  if (tid < nvalid) {
    mystart = ncur[tid];                     // local
    mydeg = ncnt[tid];
    int db = mydeg > 63 ? 63 : mydeg;
    atomicAdd(&dcnt[db], 1);
  }
  __syncthreads();
  if (tid == 0) {
    int a = 0;
    #pragma unroll
    for (int j = 0; j < 64; ++j) { int t = dcnt[j]; dcur[j] = a; a += t; }
  }
  __syncthreads();
  if (tid < nvalid) {
    int db = mydeg > 63 ? 63 : mydeg;
    int rank = atomicAdd(&dcur[db], 1);
    unsigned nd = (unsigned)(node0 + tid) | ((unsigned)mydeg << 16);
    pinfoL[rank] = make_uint2((unsigned)mystart, nd);
    permInfo[(size_t)b * BKT_NODES + rank] = make_uint2((unsigned)(gb + mystart), nd);
  }
  __syncthreads();
  for (int i = tid; i < c; i += 256) {
    unsigned p = bb[i];
    int slot = atomicAdd(&ncur[(p >> 16) & 127], 1);
    unsigned short sv = (unsigned short)(p & 0xFFFFu);
    colL[slot] = sv;
    col[gb + slot] = sv;                     // global copy for gather2
  }
  __syncthreads();

  // ----- Phase B: gather1 (slice-phased fp8, 8-lane groups) -----
  int grp = (tid & 63) >> 3;                 // group within wave 0..7
  int wv = tid >> 6;                         // wave 0..3
  int s8 = tid & 7;                          // uint2 slot (dims s8*8..s8*8+7)
  int gidx = wv * 8 + grp;                   // group id 0..31
  #pragma unroll
  for (int slice = 0; slice < 2; ++slice) {
    const uint2* Y2 = (const uint2*)(Ysfp + (size_t)slice * N_PAD * 64);
    #pragma unroll
    for (int pass = 0; pass < 4; ++pass) {
      uint2 pi = pinfoL[pass * 32 + gidx];
      int node = pi.y & 0xFFFFu;
      if (node == 0xFFFF) continue;
      int i = (int)pi.x;
      int end = i + (int)(pi.y >> 16);
      float4 a0 = make_float4(0.f, 0.f, 0.f, 0.f);
      float4 a1 = make_float4(0.f, 0.f, 0.f, 0.f);
      {
        uint2 u = Y2[(size_t)node * 8 + s8];
        ACC_FP8(a0, a1, u);
      }
      for (; i + 3 < end; i += 4) {
        int s0 = colL[i], s1 = colL[i + 1], s2 = colL[i + 2], s3 = colL[i + 3];
        uint2 u0 = Y2[(size_t)s0 * 8 + s8];
        uint2 u1 = Y2[(size_t)s1 * 8 + s8];
        uint2 u2 = Y2[(size_t)s2 * 8 + s8];
        uint2 u3 = Y2[(size_t)s3 * 8 + s8];
        ACC_FP8(a0, a1, u0); ACC_FP8(a0, a1, u1);
        ACC_FP8(a0, a1, u2); ACC_FP8(a0, a1, u3);
      }
      for (; i < end; ++i) {
        uint2 u = Y2[(size_t)colL[i] * 8 + s8];
        ACC_FP8(a0, a1, u);
      }
      uint4 p;
      p.x = bfpk(fmaxf(a0.x, 0.f), fmaxf(a0.y, 0.f));
      p.y = bfpk(fmaxf(a0.z, 0.f), fmaxf(a0.w, 0.f));
      p.z = bfpk(fmaxf(a1.x, 0.f), fmaxf(a1.y, 0.f));
      p.w = bfpk(fmaxf(a1.z, 0.f), fmaxf(a1.w, 0.f));
      ((uint4*)h1bf)[(size_t)node * 16 + slice * 8 + s8] = p;
    }
  }
}

// ---------------------------------------------------------------------------
// gather2 (degree-ordered group-per-node): 8 lanes own one node; lane s covers
// uint2 slot s, lanes 0-1 also slots 8-9 (80B row). Z is 4MB -> L2-resident.
// ---------------------------------------------------------------------------
__global__ __launch_bounds__(256) void gather2_kernel(const unsigned short* __restrict__ Zbf,
                                                      const unsigned short* __restrict__ col,
                                                      const uint2* __restrict__ permInfo,
                                                      float* __restrict__ outp) {
  int lane = threadIdx.x & 63;
  int wv = threadIdx.x >> 6;
  int g = lane >> 3, s = lane & 7;
  int slot = blockIdx.x * 32 + wv * 8 + g;
  uint2 pi = permInfo[slot];
  int node = pi.y & 0xFFFFu;
  if (node == 0xFFFF) return;
  int i = (int)pi.x;
  int end = i + (int)(pi.y >> 16);
  const uint2* Z2 = (const uint2*)Zbf;
  bool ex = s < 2;
  float4 acc = make_float4(0.f, 0.f, 0.f, 0.f);
  float4 acc2 = make_float4(0.f, 0.f, 0.f, 0.f);
  {
    uint2 u = Z2[(size_t)node * 10 + s];
    ACC_BF4F(acc, u);
    if (ex) { uint2 v = Z2[(size_t)node * 10 + 8 + s]; ACC_BF4F(acc2, v); }
  }
  for (; i + 1 < end; i += 2) {
    int s0 = col[i], s1 = col[i + 1];
    uint2 u0 = Z2[(size_t)s0 * 10 + s];
    uint2 u1 = Z2[(size_t)s1 * 10 + s];
    ACC_BF4F(acc, u0); ACC_BF4F(acc, u1);
    if (ex) {
      uint2 v0 = Z2[(size_t)s0 * 10 + 8 + s];
      uint2 v1 = Z2[(size_t)s1 * 10 + 8 + s];
      ACC_BF4F(acc2, v0); ACC_BF4F(acc2, v1);
    }
  }
  for (; i < end; ++i) {
    int s0 = col[i];
    uint2 u0 = Z2[(size_t)s0 * 10 + s];
    ACC_BF4F(acc, u0);
    if (ex) { uint2 v0 = Z2[(size_t)s0 * 10 + 8 + s]; ACC_BF4F(acc2, v0); }
  }
  float4* o4 = (float4*)(outp + (size_t)node * 40);
  o4[s] = acc;
  if (ex) o4[8 + s] = acc2;
}

// ---------------------------------------------------------------------------
// MFMA GEMM2: Z[n][c] = sum_k h1[n][k]*W2[c][k], c<40 (3 tiles, padded 48).
// ---------------------------------------------------------------------------
__global__ __launch_bounds__(256) void gemm2_kernel(const unsigned short* __restrict__ h1bf,
                                                    const unsigned short* __restrict__ W2bf,
                                                    unsigned short* __restrict__ Zbf) {
  __shared__ unsigned short Zsh[64 * 40];
  int tid = threadIdx.x;
  int wave = tid >> 6, lane = tid & 63;
  int rl = lane & 15, kg = lane >> 4;
  int n0 = blockIdx.x * 64;
  int rowg = n0 + wave * 16 + rl;
  int row = (rowg < N_NODES) ? rowg : (N_NODES - 1);
  f32x4 acc[3];
  #pragma unroll
  for (int t = 0; t < 3; ++t) acc[t] = (f32x4)(0.f);
  #pragma unroll
  for (int kk = 0; kk < 4; ++kk) {
    int k0 = kk * 32 + kg * 8;
    short8 a = *(const short8*)(h1bf + (size_t)row * 128 + k0);
    #pragma unroll
    for (int t = 0; t < 3; ++t) {
      short8 b = *(const short8*)(W2bf + (t * 16 + rl) * 128 + k0);
      acc[t] = __builtin_amdgcn_mfma_f32_16x16x32_bf16(a, b, acc[t], 0, 0, 0);
    }
  }
  #pragma unroll
  for (int t = 0; t < 3; ++t) {
    int c = t * 16 + rl;
    if (c < 40) {
      #pragma unroll
      for (int reg = 0; reg < 4; ++reg)
        Zsh[(wave * 16 + kg * 4 + reg) * 40 + c] = (unsigned short)bfr(acc[t][reg]);
    }
  }
  __syncthreads();
  int rows = N_NODES - n0; if (rows > 64) rows = 64;
  unsigned* dst = (unsigned*)Zbf + (size_t)n0 * 20;
  const unsigned* src = (const unsigned*)Zsh;
  for (int i = tid; i < rows * 20; i += 256) dst[i] = src[i];
}

// ---------------------------------------------------------------------------
extern "C" void kernel_launch(void* const* d_in, const int* in_sizes, int n_in,
                              void* d_out, int out_size, void* d_ws, size_t ws_size,
                              hipStream_t stream) {
  const float* x  = (const float*)d_in[0];
  const void*  ei = d_in[1];
  const float* W1 = (const float*)d_in[2];
  const float* W2 = (const float*)d_in[3];
  float* out = (float*)d_out;

  // ws layout (4-byte units)
  int* resv   = (int*)d_ws;                         // 1024 (zeroed by prep blk 0)
  unsigned* binned = (unsigned*)(resv + 1024);      // NBKT*CAP = 1,601,536
  unsigned short* col = (unsigned short*)(binned + (size_t)NBKT * CAP); // 800000 ushort
  uint2* permInfo = (uint2*)(col + N_EDGES);        // NPERM uint2 (8B aligned)
  unsigned char* Ysfp = (unsigned char*)(permInfo + NPERM);  // 2*N_PAD*64 fp8 (6.4MB)
  unsigned short* h1bf = (unsigned short*)(Ysfp + (size_t)2 * N_PAD * 64);  // 6.4M bf16
  unsigned short* W1bf = h1bf + (size_t)N_NODES * 128;   // 16384 bf16
  unsigned short* W2bf = W1bf + 128 * 128;          // 48*128 bf16 (padded)
  unsigned short* Zbf  = (unsigned short*)Ysfp;     // Z (4MB) reuses dead Ys region

  prep_kernel<<<89, 256, 0, stream>>>(W1, W2, resv, W1bf, W2bf);
  binGemm1_kernel<<<NBIN_BLOCKS + GEMM1_NB, 256, 0, stream>>>(ei, resv, binned,
                                                              x, W1bf, Ysfp);
  csrGather1_kernel<<<NBKT, 256, 0, stream>>>(binned, resv, col, permInfo,
                                              Ysfp, h1bf);
  gemm2_kernel<<<GEMM1_NB, 256, 0, stream>>>(h1bf, W2bf, Zbf);
  gather2_kernel<<<NB32P, 256, 0, stream>>>(Zbf, col, permInfo, out);
}

// Round 16
// 96.415 us; speedup vs baseline: 1.0483x; 1.0483x over previous
//
#include <hip/hip_runtime.h>

#define N_NODES 50000
#define N_EDGES 800000
#define BSHIFT 7                                   // 128 nodes per bucket
#define BKT_NODES 128
#define NBKT   ((N_NODES + BKT_NODES - 1) >> BSHIFT)   // 391
#define CAP    4096                                // padded slots per bucket
#define CHUNK_EDGES 8192
#define NBIN_BLOCKS ((N_EDGES + CHUNK_EDGES - 1) / CHUNK_EDGES)  // 98
#define NPERM  (NBKT * BKT_NODES)                  // 50048
#define NB32P  (NPERM / 32)                        // 1564 blocks (32 perm slots each)
#define N_PAD  50048                               // padded node count (slice regions)
#define GEMM1_NB ((N_NODES + 63) / 64)             // 782

typedef __attribute__((ext_vector_type(8))) short short8;   // 8 bf16 (4 VGPRs)
typedef __attribute__((ext_vector_type(4))) float f32x4;    // MFMA acc
typedef __attribute__((ext_vector_type(2))) float f32x2;    // fp8 cvt result

__device__ __forceinline__ int load_idx(const void* ei, int is64, long long pos) {
  return is64 ? (int)((const long long*)ei)[pos] : ((const int*)ei)[pos];
}

// bf16 (RNE) pack helpers
__device__ __forceinline__ unsigned bfr(float f) {
  unsigned u = __float_as_uint(f);
  return (u + 0x7FFFu + ((u >> 16) & 1u)) >> 16;
}
__device__ __forceinline__ unsigned bfpk(float lo, float hi) {
  return bfr(lo) | (bfr(hi) << 16);
}
// FAST bf16 unpack-accumulate (gather2)
#define ACC_BF4F(acc, u)                                                   \
  acc.x += __uint_as_float((u).x << 16);                                   \
  acc.y += __uint_as_float((u).x);                                         \
  acc.z += __uint_as_float((u).y << 16);                                   \
  acc.w += __uint_as_float((u).y);

// fp8 e4m3 (OCP on gfx950) unpack-accumulate: uint2 = 8 fp8 -> 8 f32 adds
#define ACC_FP8(a0, a1, u) {                                               \
  f32x2 t0 = __builtin_amdgcn_cvt_pk_f32_fp8((int)(u).x, false);           \
  f32x2 t1 = __builtin_amdgcn_cvt_pk_f32_fp8((int)(u).x, true);            \
  f32x2 t2 = __builtin_amdgcn_cvt_pk_f32_fp8((int)(u).y, false);           \
  f32x2 t3 = __builtin_amdgcn_cvt_pk_f32_fp8((int)(u).y, true);            \
  a0.x += t0.x; a0.y += t0.y; a0.z += t1.x; a0.w += t1.y;                  \
  a1.x += t2.x; a1.y += t2.y; a1.z += t3.x; a1.w += t3.y; }

// ---------------------------------------------------------------------------
// prep: block 0 zeroes resv; blocks 1..88 cast W1/W2 to bf16 (native [o][k],
// W2 padded to 48 rows). Stream order guarantees resv=0 before binGemm1.
// ---------------------------------------------------------------------------
__global__ __launch_bounds__(256) void prep_kernel(const float* __restrict__ W1,
                                                   const float* __restrict__ W2,
                                                   int* __restrict__ resv,
                                                   unsigned short* __restrict__ W1bf,
                                                   unsigned short* __restrict__ W2bf) {
  int b = blockIdx.x, tid = threadIdx.x;
  if (b == 0) {
    ((int4*)resv)[tid] = make_int4(0, 0, 0, 0);   // 1024 ints
    return;
  }
  int j = (b - 1) * 256 + tid;                    // [0, 22528)
  if (j < 128 * 128) {
    W1bf[j] = (unsigned short)bfr(W1[j]);
  } else {
    int jj = j - 128 * 128;                       // [0, 6144)
    int c = jj >> 7, k = jj & 127;
    W2bf[jj] = (c < 40) ? (unsigned short)bfr(W2[c * 128 + k]) : 0;
  }
}

// ---------------------------------------------------------------------------
// Merged binPlace + gemm1 (independent work; binPlace's memory latency hides
// under gemm1's MFMA waves).
// Blocks [0, NBIN_BLOCKS): bucket partition, CHUNK=8192 edges/block.
//   pk = src | dstlow<<16 | bk<<23.
// Blocks [NBIN_BLOCKS, +GEMM1_NB): MFMA GEMM1 Y[n][o] = sum_k x[n][k]W1[o][k],
//   epilogue writes SLICE-MAJOR fp8 Ys: 2 regions of [N_PAD][64] e4m3.
// ---------------------------------------------------------------------------
__global__ __launch_bounds__(256) void binGemm1_kernel(const void* __restrict__ ei,
                                                       int* __restrict__ resv,
                                                       unsigned* __restrict__ binned,
                                                       const float* __restrict__ xin,
                                                       const unsigned short* __restrict__ W1bf,
                                                       unsigned char* __restrict__ Ysfp) {
  __shared__ unsigned short Ysh[64 * 128];       // gemm1 epilogue stage (16KB)
  __shared__ int cnt[NBKT];
  __shared__ int lbase[NBKT];
  __shared__ int sflag;
  int tid = threadIdx.x;

  if (blockIdx.x < NBIN_BLOCKS) {
    // ----- binPlace part -----
    if (tid < 64) {
      const long long* e64 = (const long long*)ei;
      long long v = e64[tid];
      unsigned long long m = __ballot(v >= 0 && v < N_NODES);
      if (tid == 0) sflag = (m == ~0ull) ? 1 : 0;
    }
    for (int i = tid; i < NBKT; i += 256) cnt[i] = 0;
    __syncthreads();
    int f = sflag;
    long long base = (long long)blockIdx.x * CHUNK_EDGES;
    unsigned pk[CHUNK_EDGES / 256];
    #pragma unroll
    for (int it = 0; it < CHUNK_EDGES / 256; ++it) {
      long long e = base + it * 256 + tid;
      unsigned p = 0xFFFFFFFFu;
      if (e < N_EDGES) {
        int src = load_idx(ei, f, e);
        int dst = load_idx(ei, f, (long long)N_EDGES + e);
        int bk = dst >> BSHIFT;
        p = (unsigned)src | ((unsigned)(dst & 127) << 16) | ((unsigned)bk << 23);
        atomicAdd(&cnt[bk], 1);
      }
      pk[it] = p;
    }
    __syncthreads();
    for (int i = tid; i < NBKT; i += 256) {
      int c = cnt[i];
      lbase[i] = c ? (i * CAP + atomicAdd(&resv[i], c)) : 0;
      cnt[i] = 0;                                 // reuse as local cursor
    }
    __syncthreads();
    #pragma unroll
    for (int it = 0; it < CHUNK_EDGES / 256; ++it) {
      unsigned p = pk[it];
      if (p != 0xFFFFFFFFu) {
        int bk = p >> 23;
        int off = atomicAdd(&cnt[bk], 1);
        binned[lbase[bk] + off] = p & 0x7FFFFFu;  // src | dstlow<<16
      }
    }
    return;
  }

  // ----- gemm1 part -----
  int wave = tid >> 6, lane = tid & 63;
  int rl = lane & 15, kg = lane >> 4;      // kg = 0..3
  int n0 = (blockIdx.x - NBIN_BLOCKS) * 64;
  int rowg = n0 + wave * 16 + rl;
  int row = (rowg < N_NODES) ? rowg : (N_NODES - 1);
  f32x4 acc[8];
  #pragma unroll
  for (int t = 0; t < 8; ++t) acc[t] = (f32x4)(0.f);
  #pragma unroll
  for (int kk = 0; kk < 4; ++kk) {
    int k0 = kk * 32 + kg * 8;
    const float* xr = xin + (size_t)row * 128 + k0;
    float4 a0 = *(const float4*)xr;
    float4 a1 = *(const float4*)(xr + 4);
    short8 a;
    a[0] = (short)bfr(a0.x); a[1] = (short)bfr(a0.y);
    a[2] = (short)bfr(a0.z); a[3] = (short)bfr(a0.w);
    a[4] = (short)bfr(a1.x); a[5] = (short)bfr(a1.y);
    a[6] = (short)bfr(a1.z); a[7] = (short)bfr(a1.w);
    #pragma unroll
    for (int t = 0; t < 8; ++t) {
      short8 b = *(const short8*)(W1bf + (t * 16 + rl) * 128 + k0);
      acc[t] = __builtin_amdgcn_mfma_f32_16x16x32_bf16(a, b, acc[t], 0, 0, 0);
    }
  }
  // C/D: col = rl, row = kg*4 + reg (within wave's 16 rows) -> bf16 LDS stage
  #pragma unroll
  for (int t = 0; t < 8; ++t) {
    #pragma unroll
    for (int reg = 0; reg < 4; ++reg)
      Ysh[(wave * 16 + kg * 4 + reg) * 128 + t * 16 + rl] =
          (unsigned short)bfr(acc[t][reg]);
  }
  __syncthreads();
  // epilogue: LDS bf16 -> fp8 e4m3, slice-major (2 regions of [N_PAD][64])
  int rows = N_NODES - n0; if (rows > 64) rows = 64;
  uint2* dstb = (uint2*)Ysfp;
  const unsigned* ysh32 = (const unsigned*)Ysh;
  for (int i = tid; i < rows * 16; i += 256) {
    int r = i >> 4, j = i & 15;            // j = 8-dim chunk (dims j*8..j*8+7)
    int base = r * 64 + j * 4;             // uint index (2 bf16 per uint)
    unsigned u0 = ysh32[base + 0], u1 = ysh32[base + 1];
    unsigned u2 = ysh32[base + 2], u3 = ysh32[base + 3];
    float d0 = __uint_as_float(u0 << 16), d1 = __uint_as_float(u0 & 0xffff0000u);
    float d2 = __uint_as_float(u1 << 16), d3 = __uint_as_float(u1 & 0xffff0000u);
    float d4 = __uint_as_float(u2 << 16), d5 = __uint_as_float(u2 & 0xffff0000u);
    float d6 = __uint_as_float(u3 << 16), d7 = __uint_as_float(u3 & 0xffff0000u);
    int wx = __builtin_amdgcn_cvt_pk_fp8_f32(d0, d1, 0, false);
    wx = __builtin_amdgcn_cvt_pk_fp8_f32(d2, d3, wx, true);
    int wy = __builtin_amdgcn_cvt_pk_fp8_f32(d4, d5, 0, false);
    wy = __builtin_amdgcn_cvt_pk_fp8_f32(d6, d7, wy, true);
    int slice = j >> 3, cs = j & 7;
    dstb[(size_t)slice * (N_PAD * 8) + (size_t)(n0 + r) * 8 + cs] =
        make_uint2((unsigned)wx, (unsigned)wy);
  }
}

// ---------------------------------------------------------------------------
// csr: one block per bucket. Inline exclusive scan of resv -> global base;
// LDS node histogram; per-bucket DEGREE-SORT -> permInfo uint2
// {start, node|deg<<16} (sentinel 0xFFFF written for ALL 128 slots — harness
// poisons ws with 0xAA); compact bucket into col.
// ---------------------------------------------------------------------------
__global__ __launch_bounds__(256) void csr_kernel(const unsigned* __restrict__ binned,
                                                  const int* __restrict__ resv,
                                                  unsigned short* __restrict__ col,
                                                  uint2* __restrict__ permInfo) {
  __shared__ int red[256];
  __shared__ int ncnt[BKT_NODES];
  __shared__ int ncur[BKT_NODES];
  __shared__ int dcnt[64];
  __shared__ int dcur[64];
  int tid = threadIdx.x;
  int b = blockIdx.x;
  int s = 0;
  for (int i = tid; i < b; i += 256) s += resv[i];
  red[tid] = s;
  __syncthreads();
  #pragma unroll
  for (int off = 128; off > 0; off >>= 1) {
    if (tid < off) red[tid] += red[tid + off];
    __syncthreads();
  }
  int gb = red[0];
  int c = resv[b];
  if (tid < BKT_NODES) {
    ncnt[tid] = 0;
    permInfo[(size_t)b * BKT_NODES + tid] = make_uint2(0u, 0xFFFFu);
  }
  if (tid < 64) dcnt[tid] = 0;
  __syncthreads();
  const unsigned* bb = binned + (size_t)b * CAP;
  for (int i = tid; i < c; i += 256)
    atomicAdd(&ncnt[(bb[i] >> 16) & 127], 1);
  __syncthreads();
  if (tid == 0) {
    int a = gb;
    #pragma unroll
    for (int j = 0; j < BKT_NODES; ++j) { int t = ncnt[j]; ncur[j] = a; a += t; }
  }
  __syncthreads();
  int node0 = b << BSHIFT;
  int nvalid = N_NODES - node0; if (nvalid > BKT_NODES) nvalid = BKT_NODES;
  int mystart = 0, mydeg = 0;
  if (tid < nvalid) {
    mystart = ncur[tid];
    mydeg = ncnt[tid];
    int db = mydeg > 63 ? 63 : mydeg;
    atomicAdd(&dcnt[db], 1);
  }
  __syncthreads();
  if (tid == 0) {
    int a = 0;
    #pragma unroll
    for (int j = 0; j < 64; ++j) { int t = dcnt[j]; dcur[j] = a; a += t; }
  }
  __syncthreads();
  if (tid < nvalid) {
    int db = mydeg > 63 ? 63 : mydeg;
    int rank = atomicAdd(&dcur[db], 1);
    permInfo[(size_t)b * BKT_NODES + rank] =
        make_uint2((unsigned)mystart,
                   (unsigned)(node0 + tid) | ((unsigned)mydeg << 16));
  }
  __syncthreads();   // perm writes & mystart captures done before ncur mutates
  for (int i = tid; i < c; i += 256) {
    unsigned p = bb[i];
    int slot = atomicAdd(&ncur[(p >> 16) & 127], 1);
    col[slot] = (unsigned short)(p & 0xFFFFu);
  }
}

// ---------------------------------------------------------------------------
// gather1 (slice-phased fp8, degree-ordered group-per-node): 8 lanes own one
// node; lane s covers dims s*8..s*8+7 of the slice (uint2 = 8 fp8). Y slice =
// [N_PAD][64] fp8 = 3.2MB, fully XCD-L2-resident. Slice is the SLOW blockIdx
// component -> temporal phasing keeps one slice hot at a time. h1 bf16.
// ---------------------------------------------------------------------------
__global__ __launch_bounds__(256) void gather1_kernel(const unsigned char* __restrict__ Ysfp,
                                                      const unsigned short* __restrict__ col,
                                                      const uint2* __restrict__ permInfo,
                                                      unsigned short* __restrict__ h1bf) {
  int bid = blockIdx.x;
  int slice = bid / NB32P;                 // 0 or 1
  int nb = bid - slice * NB32P;
  int lane = threadIdx.x & 63;
  int wv = threadIdx.x >> 6;
  int g = lane >> 3, s8 = lane & 7;
  int slot = nb * 32 + wv * 8 + g;
  uint2 pi = permInfo[slot];
  int node = pi.y & 0xFFFFu;
  if (node == 0xFFFF) return;
  int i = (int)pi.x;
  int end = i + (int)(pi.y >> 16);
  const uint2* Y2 = (const uint2*)(Ysfp + (size_t)slice * N_PAD * 64);
  float4 a0 = make_float4(0.f, 0.f, 0.f, 0.f);
  float4 a1 = make_float4(0.f, 0.f, 0.f, 0.f);
  {
    uint2 u = Y2[(size_t)node * 8 + s8];
    ACC_FP8(a0, a1, u);
  }
  for (; i + 3 < end; i += 4) {
    int s0 = col[i], s1 = col[i + 1], s2 = col[i + 2], s3 = col[i + 3];
    uint2 u0 = Y2[(size_t)s0 * 8 + s8];
    uint2 u1 = Y2[(size_t)s1 * 8 + s8];
    uint2 u2 = Y2[(size_t)s2 * 8 + s8];
    uint2 u3 = Y2[(size_t)s3 * 8 + s8];
    ACC_FP8(a0, a1, u0); ACC_FP8(a0, a1, u1);
    ACC_FP8(a0, a1, u2); ACC_FP8(a0, a1, u3);
  }
  for (; i < end; ++i) {
    uint2 u = Y2[(size_t)col[i] * 8 + s8];
    ACC_FP8(a0, a1, u);
  }
  uint4 p;
  p.x = bfpk(fmaxf(a0.x, 0.f), fmaxf(a0.y, 0.f));
  p.y = bfpk(fmaxf(a0.z, 0.f), fmaxf(a0.w, 0.f));
  p.z = bfpk(fmaxf(a1.x, 0.f), fmaxf(a1.y, 0.f));
  p.w = bfpk(fmaxf(a1.z, 0.f), fmaxf(a1.w, 0.f));
  ((uint4*)h1bf)[(size_t)node * 16 + slice * 8 + s8] = p;
}

// ---------------------------------------------------------------------------
// gather2 (degree-ordered group-per-node): 8 lanes own one node; lane s covers
// uint2 slot s, lanes 0-1 also slots 8-9 (80B row). Z is 4MB -> L2-resident.
// ---------------------------------------------------------------------------
__global__ __launch_bounds__(256) void gather2_kernel(const unsigned short* __restrict__ Zbf,
                                                      const unsigned short* __restrict__ col,
                                                      const uint2* __restrict__ permInfo,
                                                      float* __restrict__ outp) {
  int lane = threadIdx.x & 63;
  int wv = threadIdx.x >> 6;
  int g = lane >> 3, s = lane & 7;
  int slot = blockIdx.x * 32 + wv * 8 + g;
  uint2 pi = permInfo[slot];
  int node = pi.y & 0xFFFFu;
  if (node == 0xFFFF) return;
  int i = (int)pi.x;
  int end = i + (int)(pi.y >> 16);
  const uint2* Z2 = (const uint2*)Zbf;
  bool ex = s < 2;
  float4 acc = make_float4(0.f, 0.f, 0.f, 0.f);
  float4 acc2 = make_float4(0.f, 0.f, 0.f, 0.f);
  {
    uint2 u = Z2[(size_t)node * 10 + s];
    ACC_BF4F(acc, u);
    if (ex) { uint2 v = Z2[(size_t)node * 10 + 8 + s]; ACC_BF4F(acc2, v); }
  }
  for (; i + 1 < end; i += 2) {
    int s0 = col[i], s1 = col[i + 1];
    uint2 u0 = Z2[(size_t)s0 * 10 + s];
    uint2 u1 = Z2[(size_t)s1 * 10 + s];
    ACC_BF4F(acc, u0); ACC_BF4F(acc, u1);
    if (ex) {
      uint2 v0 = Z2[(size_t)s0 * 10 + 8 + s];
      uint2 v1 = Z2[(size_t)s1 * 10 + 8 + s];
      ACC_BF4F(acc2, v0); ACC_BF4F(acc2, v1);
    }
  }
  for (; i < end; ++i) {
    int s0 = col[i];
    uint2 u0 = Z2[(size_t)s0 * 10 + s];
    ACC_BF4F(acc, u0);
    if (ex) { uint2 v0 = Z2[(size_t)s0 * 10 + 8 + s]; ACC_BF4F(acc2, v0); }
  }
  float4* o4 = (float4*)(outp + (size_t)node * 40);
  o4[s] = acc;
  if (ex) o4[8 + s] = acc2;
}

// ---------------------------------------------------------------------------
// MFMA GEMM2: Z[n][c] = sum_k h1[n][k]*W2[c][k], c<40 (3 tiles, padded 48).
// ---------------------------------------------------------------------------
__global__ __launch_bounds__(256) void gemm2_kernel(const unsigned short* __restrict__ h1bf,
                                                    const unsigned short* __restrict__ W2bf,
                                                    unsigned short* __restrict__ Zbf) {
  __shared__ unsigned short Zsh[64 * 40];
  int tid = threadIdx.x;
  int wave = tid >> 6, lane = tid & 63;
  int rl = lane & 15, kg = lane >> 4;
  int n0 = blockIdx.x * 64;
  int rowg = n0 + wave * 16 + rl;
  int row = (rowg < N_NODES) ? rowg : (N_NODES - 1);
  f32x4 acc[3];
  #pragma unroll
  for (int t = 0; t < 3; ++t) acc[t] = (f32x4)(0.f);
  #pragma unroll
  for (int kk = 0; kk < 4; ++kk) {
    int k0 = kk * 32 + kg * 8;
    short8 a = *(const short8*)(h1bf + (size_t)row * 128 + k0);
    #pragma unroll
    for (int t = 0; t < 3; ++t) {
      short8 b = *(const short8*)(W2bf + (t * 16 + rl) * 128 + k0);
      acc[t] = __builtin_amdgcn_mfma_f32_16x16x32_bf16(a, b, acc[t], 0, 0, 0);
    }
  }
  #pragma unroll
  for (int t = 0; t < 3; ++t) {
    int c = t * 16 + rl;
    if (c < 40) {
      #pragma unroll
      for (int reg = 0; reg < 4; ++reg)
        Zsh[(wave * 16 + kg * 4 + reg) * 40 + c] = (unsigned short)bfr(acc[t][reg]);
    }
  }
  __syncthreads();
  int rows = N_NODES - n0; if (rows > 64) rows = 64;
  unsigned* dst = (unsigned*)Zbf + (size_t)n0 * 20;
  const unsigned* src = (const unsigned*)Zsh;
  for (int i = tid; i < rows * 20; i += 256) dst[i] = src[i];
}

// ---------------------------------------------------------------------------
extern "C" void kernel_launch(void* const* d_in, const int* in_sizes, int n_in,
                              void* d_out, int out_size, void* d_ws, size_t ws_size,
                              hipStream_t stream) {
  const float* x  = (const float*)d_in[0];
  const void*  ei = d_in[1];
  const float* W1 = (const float*)d_in[2];
  const float* W2 = (const float*)d_in[3];
  float* out = (float*)d_out;

  // ws layout (4-byte units)
  int* resv   = (int*)d_ws;                         // 1024 (zeroed by prep blk 0)
  unsigned* binned = (unsigned*)(resv + 1024);      // NBKT*CAP = 1,601,536
  unsigned short* col = (unsigned short*)(binned + (size_t)NBKT * CAP); // 800000 ushort
  uint2* permInfo = (uint2*)(col + N_EDGES);        // NPERM uint2 (8B aligned)
  unsigned char* Ysfp = (unsigned char*)(permInfo + NPERM);  // 2*N_PAD*64 fp8 (6.4MB)
  unsigned short* h1bf = (unsigned short*)(Ysfp + (size_t)2 * N_PAD * 64);  // 6.4M bf16
  unsigned short* W1bf = h1bf + (size_t)N_NODES * 128;   // 16384 bf16
  unsigned short* W2bf = W1bf + 128 * 128;          // 48*128 bf16 (padded)
  unsigned short* Zbf  = (unsigned short*)Ysfp;     // Z (4MB) reuses dead Ys region

  prep_kernel<<<89, 256, 0, stream>>>(W1, W2, resv, W1bf, W2bf);
  binGemm1_kernel<<<NBIN_BLOCKS + GEMM1_NB, 256, 0, stream>>>(ei, resv, binned,
                                                              x, W1bf, Ysfp);
  csr_kernel<<<NBKT, 256, 0, stream>>>(binned, resv, col, permInfo);
  gather1_kernel<<<2 * NB32P, 256, 0, stream>>>(Ysfp, col, permInfo, h1bf);
  gemm2_kernel<<<GEMM1_NB, 256, 0, stream>>>(h1bf, W2bf, Zbf);
  gather2_kernel<<<NB32P, 256, 0, stream>>>(Zbf, col, permInfo, out);
}